// Round 12
// baseline (1495.568 us; speedup 1.0000x reference)
//
#include <hip/hip_runtime.h>
#include <math.h>

#define N_ROWS 4096
#define E_DIM  512
#define C_CLS  50257
#define NCT2   786          // partials per row: 393 col-tiles * 2 wave-halves
#define NTILE  393          // ceil(50257/128)
#define COS_M  (-0.6536436208636119f)   // cos(4.0)
#define SIN_M  (-0.7568024953079282f)   // sin(4.0)
#define EPSN   1e-12f

#define WAITCNT_LGKM0 0xC07F   // lgkmcnt(0), vmcnt/exp ignored

typedef __bf16 bf16x8 __attribute__((ext_vector_type(8)));
typedef float  f32x4  __attribute__((ext_vector_type(4)));
typedef unsigned short ushort8 __attribute__((ext_vector_type(8)));

__device__ inline unsigned short f2bf(float f) {
  unsigned int u = __float_as_uint(f);
  u += 0x7FFFu + ((u >> 16) & 1u);     // round-to-nearest-even
  return (unsigned short)(u >> 16);
}

// Row L2-normalize f32 -> bf16 for BOTH w and x in one launch (one dispatch
// less). Rows [0, C_CLS) -> w/nw; rows [C_CLS, C_CLS+N_ROWS) -> x/nx.
// Wave-private (no barriers): 4 rows/block, 1 wave/row.
__global__ __launch_bounds__(256) void k_norm(const float* __restrict__ w,
                                              const float* __restrict__ x,
                                              unsigned short* __restrict__ nw,
                                              unsigned short* __restrict__ nx) {
  int row = blockIdx.x * 4 + (threadIdx.x >> 6);
  const float* src;
  unsigned short* dst;
  if (row < C_CLS) {
    src = w + (size_t)row * E_DIM;
    dst = nw + (size_t)row * E_DIM;
  } else {
    int r = row - C_CLS;
    if (r >= N_ROWS) return;
    src = x + (size_t)r * E_DIM;
    dst = nx + (size_t)r * E_DIM;
  }
  int lane = threadIdx.x & 63;
  const float4* p = (const float4*)src;
  float4 v0 = p[lane * 2], v1 = p[lane * 2 + 1];
  float ss = v0.x*v0.x + v0.y*v0.y + v0.z*v0.z + v0.w*v0.w
           + v1.x*v1.x + v1.y*v1.y + v1.z*v1.z + v1.w*v1.w;
  #pragma unroll
  for (int m = 32; m > 0; m >>= 1) ss += __shfl_xor(ss, m, 64);
  float inv = 1.0f / fmaxf(sqrtf(ss), EPSN);
  ushort8 o;
  o[0]=f2bf(v0.x*inv); o[1]=f2bf(v0.y*inv); o[2]=f2bf(v0.z*inv); o[3]=f2bf(v0.w*inv);
  o[4]=f2bf(v1.x*inv); o[5]=f2bf(v1.y*inv); o[6]=f2bf(v1.z*inv); o[7]=f2bf(v1.w*inv);
  *(ushort8*)(dst + lane * 8) = o;
}

// 128x128-tile GEMM (cos = nx.nw^T) + fused exp-sum.  [R8 skeleton]
// Register-staged pipeline — NO global_load_lds, so the barrier drains lgkm
// ONLY and in-flight global loads (stage k+2) cross it freely.
// 4 waves (2x2 quadrants of 64x64). BK=32, 16 stages, double-buffered LDS.
// Stage k: ds_read frags buf p; ds_write reg set (k+1)&1 -> buf p^1 (precise
// per-reg vmcnt waits, loads issued 2 stages ago); issue global loads k+2;
// 16 MFMA; lgkmcnt(0); s_barrier.
// Occupancy: 32 KB LDS x 5 = 160 KiB exactly -> __launch_bounds__(256,5)
// targets 5 blocks/CU (R8's (256,4) reached only ~3.5; throughput is
// resident_blocks x stage_critical_path, so this is the main lever).
// No max-prescan: cos in [-1,1] so exp() is safe; partials are plain sums.
__global__ __launch_bounds__(256, 5) void k_gemm(const unsigned short* __restrict__ nx,
                                                 const unsigned short* __restrict__ nw,
                                                 const int* __restrict__ label,
                                                 float* __restrict__ pl,
                                                 float* __restrict__ tbf) {
  __shared__ bf16x8 ldsA[2][8 * 64];   // 2 x 8 KB
  __shared__ bf16x8 ldsB[2][8 * 64];   // 2 x 8 KB

  int rtile = blockIdx.x;              // 0..31 fastest -> B reuse in L2/L3
  int ctile = blockIdx.y;              // 0..392
  int tid = threadIdx.x;
  int wave = tid >> 6;
  int lane = tid & 63;
  int q = lane >> 4;
  int l15 = lane & 15;
  int wr = wave >> 1;
  int wc = wave & 1;
  int rowTile = rtile * 128;
  int colTile = ctile * 128;

  // Chunk c = wave*2+t covers rows/cols [c*16,+16); lane (q,l15) supplies
  // row c*16+l15, elems kt*32 + q*8 .. +7 (16 B).
  const unsigned short* gA[2];
  const unsigned short* gB[2];
  #pragma unroll
  for (int t = 0; t < 2; t++) {
    int c = wave * 2 + t;
    gA[t] = nx + (size_t)(rowTile + c * 16 + l15) * E_DIM + q * 8;
    int cls = colTile + c * 16 + l15;
    if (cls >= C_CLS) cls = C_CLS - 1;          // clamp; masked in epilogue
    gB[t] = nw + (size_t)cls * E_DIM + q * 8;
  }

  // Staging registers: parity sets — set s&1 holds stage s data.
  bf16x8 rA[2][2], rB[2][2];
  #pragma unroll
  for (int t = 0; t < 2; t++) {
    rA[0][t] = *(const bf16x8*)(gA[t]);
    rB[0][t] = *(const bf16x8*)(gB[t]);
    rA[1][t] = *(const bf16x8*)(gA[t] + 32);
    rB[1][t] = *(const bf16x8*)(gB[t] + 32);
  }
  // Write stage 0 into buf 0 (compiler inserts precise vmcnt waits).
  #pragma unroll
  for (int t = 0; t < 2; t++) {
    int c = wave * 2 + t;
    ldsA[0][c * 64 + lane] = rA[0][t];
    ldsB[0][c * 64 + lane] = rB[0][t];
  }
  __builtin_amdgcn_s_waitcnt(WAITCNT_LGKM0);
  __builtin_amdgcn_s_barrier();

  f32x4 acc[4][4] = {};

  #pragma unroll
  for (int kt = 0; kt < 16; kt++) {
    int p = kt & 1;
    // Fragments for stage kt.
    bf16x8 afr[4], bfr[4];
    #pragma unroll
    for (int i = 0; i < 4; i++)
      afr[i] = ldsA[p][(wr * 4 + i) * 64 + lane];
    #pragma unroll
    for (int j = 0; j < 4; j++)
      bfr[j] = ldsB[p][(wc * 4 + j) * 64 + lane];
    // Stage kt+1: regs -> buf p^1.
    if (kt + 1 < 16) {
      #pragma unroll
      for (int t = 0; t < 2; t++) {
        int c = wave * 2 + t;
        ldsA[p ^ 1][c * 64 + lane] = rA[(kt + 1) & 1][t];
        ldsB[p ^ 1][c * 64 + lane] = rB[(kt + 1) & 1][t];
      }
    }
    // Stage kt+2: global -> regs (set (kt+2)&1 == p).
    if (kt + 2 < 16) {
      #pragma unroll
      for (int t = 0; t < 2; t++) {
        rA[p][t] = *(const bf16x8*)(gA[t] + (kt + 2) * 32);
        rB[p][t] = *(const bf16x8*)(gB[t] + (kt + 2) * 32);
      }
    }
    #pragma unroll
    for (int i = 0; i < 4; i++)
      #pragma unroll
      for (int j = 0; j < 4; j++)
        acc[i][j] = __builtin_amdgcn_mfma_f32_16x16x32_bf16(afr[i], bfr[j],
                                                            acc[i][j], 0, 0, 0);
    __builtin_amdgcn_s_waitcnt(WAITCNT_LGKM0);   // all LDS ops retired (vmcnt free)
    __builtin_amdgcn_s_barrier();
  }

  // Epilogue: C/D layout row = 4*q + reg (within 16), col = l15.
  // Wave covers rows [rowTile + wr*64, +64), cols [colTile + wc*64, +64).
  int colW = colTile + wc * 64;
  #pragma unroll
  for (int msub = 0; msub < 4; msub++) {
    #pragma unroll
    for (int reg = 0; reg < 4; reg++) {
      int grow = rowTile + wr * 64 + msub * 16 + 4 * q + reg;
      int lab = label[grow];
      float e = 0.f;
      #pragma unroll
      for (int ns = 0; ns < 4; ns++) {
        int col = colW + ns * 16 + l15;
        float v = acc[msub][ns][reg];
        if (col < C_CLS) {
          e += __expf(v);
          if (col == lab) tbf[grow] = v;   // bf16-GEMM cos at label position
        }
      }
      #pragma unroll
      for (int m = 1; m < 16; m <<= 1) e += __shfl_xor(e, m, 64);
      if (l15 == 0) pl[(size_t)grow * NCT2 + (size_t)ctile * 2 + wc] = e;
    }
  }
}

// Per row: sum exp-partials, precise fp32 target cosine (fused), swap in
// margin logit, mean-reduce. 1 block/row, 256 thr.
__global__ __launch_bounds__(256) void k_reduce(const float* __restrict__ pl,
                                                const float* __restrict__ x,
                                                const float* __restrict__ w,
                                                const int* __restrict__ label,
                                                const float* __restrict__ tbf,
                                                float* __restrict__ out) {
  int row = blockIdx.x;
  int tid = threadIdx.x;
  int lab = label[row];
  float s = 0.f;
  for (int j = tid; j < NCT2; j += 256) s += pl[(size_t)row * NCT2 + j];
  const float2* px = (const float2*)(x + (size_t)row * E_DIM);
  const float2* pw = (const float2*)(w + (size_t)lab * E_DIM);
  float2 a = px[tid], b = pw[tid];
  float sx = a.x*a.x + a.y*a.y;
  float sw = b.x*b.x + b.y*b.y;
  float sd = a.x*b.x + a.y*b.y;
  #pragma unroll
  for (int off = 32; off > 0; off >>= 1) {
    s  += __shfl_down(s, off, 64);
    sx += __shfl_down(sx, off, 64);
    sw += __shfl_down(sw, off, 64);
    sd += __shfl_down(sd, off, 64);
  }
  __shared__ float sb[4][4];
  if ((tid & 63) == 0) {
    int wv = tid >> 6;
    sb[0][wv] = s; sb[1][wv] = sx; sb[2][wv] = sw; sb[3][wv] = sd;
  }
  __syncthreads();
  if (tid == 0) {
    float S  = sb[0][0] + sb[0][1] + sb[0][2] + sb[0][3];
    float SX = sb[1][0] + sb[1][1] + sb[1][2] + sb[1][3];
    float SW = sb[2][0] + sb[2][1] + sb[2][2] + sb[2][3];
    float SD = sb[3][0] + sb[3][1] + sb[3][2] + sb[3][3];
    float t = SD / (fmaxf(sqrtf(SX), EPSN) * fmaxf(sqrtf(SW), EPSN));
    float tb = tbf[row];
    float sint = sqrtf(fmaxf(0.f, 1.f - t * t));
    float cosm = t * COS_M - sint * SIN_M;
    float Sp = S - __expf(tb) + __expf(cosm);   // replace target logit
    float loss = logf(Sp) - cosm;
    atomicAdd(out, loss * (1.0f / N_ROWS));
  }
}

extern "C" void kernel_launch(void* const* d_in, const int* in_sizes, int n_in,
                              void* d_out, int out_size, void* d_ws, size_t ws_size,
                              hipStream_t stream) {
  const float* x = (const float*)d_in[0];
  const int* label = (const int*)d_in[1];
  const float* w = (const float*)d_in[2];
  float* out = (float*)d_out;
  char* ws = (char*)d_ws;

  size_t off = 0;
  unsigned short* nx = (unsigned short*)(ws + off); off += (size_t)N_ROWS * E_DIM * 2;  // 4 MB
  unsigned short* nw = (unsigned short*)(ws + off); off += (size_t)C_CLS * E_DIM * 2;   // 51.5 MB
  float* tbf = (float*)(ws + off); off += (size_t)N_ROWS * 4;
  float* pl  = (float*)(ws + off); off += (size_t)N_ROWS * NCT2 * 4;                    // 12.9 MB

  hipMemsetAsync(d_out, 0, sizeof(float), stream);
  k_norm<<<(C_CLS + N_ROWS + 3) / 4, 256, 0, stream>>>(w, x, nw, nx);
  dim3 g(N_ROWS / 128, NTILE);
  k_gemm<<<g, 256, 0, stream>>>(nx, nw, label, pl, tbf);
  k_reduce<<<N_ROWS, 256, 0, stream>>>(pl, x, w, label, tbf, out);
}

// Round 13
// 762.921 us; speedup vs baseline: 1.9603x; 1.9603x over previous
//
#include <hip/hip_runtime.h>
#include <math.h>

#define N_ROWS 4096
#define E_DIM  512
#define C_CLS  50257
#define NCT2   786          // partials per row: 393 col-tiles * 2 wave-halves
#define NTILE  393          // ceil(50257/128)
#define COS_M  (-0.6536436208636119f)   // cos(4.0)
#define SIN_M  (-0.7568024953079282f)   // sin(4.0)
#define EPSN   1e-12f

#define WAITCNT_LGKM0 0xC07F   // lgkmcnt(0), vmcnt/exp ignored

typedef __bf16 bf16x8 __attribute__((ext_vector_type(8)));
typedef float  f32x4  __attribute__((ext_vector_type(4)));
typedef unsigned short ushort8 __attribute__((ext_vector_type(8)));

__device__ inline unsigned short f2bf(float f) {
  unsigned int u = __float_as_uint(f);
  u += 0x7FFFu + ((u >> 16) & 1u);     // round-to-nearest-even
  return (unsigned short)(u >> 16);
}

// Row L2-normalize f32 -> bf16 for BOTH w and x in one launch.
// Rows [0, C_CLS) -> w/nw; rows [C_CLS, C_CLS+N_ROWS) -> x/nx.
// Wave-private (no barriers): 4 rows/block, 1 wave/row.
__global__ __launch_bounds__(256) void k_norm(const float* __restrict__ w,
                                              const float* __restrict__ x,
                                              unsigned short* __restrict__ nw,
                                              unsigned short* __restrict__ nx) {
  int row = blockIdx.x * 4 + (threadIdx.x >> 6);
  const float* src;
  unsigned short* dst;
  if (row < C_CLS) {
    src = w + (size_t)row * E_DIM;
    dst = nw + (size_t)row * E_DIM;
  } else {
    int r = row - C_CLS;
    if (r >= N_ROWS) return;
    src = x + (size_t)r * E_DIM;
    dst = nx + (size_t)r * E_DIM;
  }
  int lane = threadIdx.x & 63;
  const float4* p = (const float4*)src;
  float4 v0 = p[lane * 2], v1 = p[lane * 2 + 1];
  float ss = v0.x*v0.x + v0.y*v0.y + v0.z*v0.z + v0.w*v0.w
           + v1.x*v1.x + v1.y*v1.y + v1.z*v1.z + v1.w*v1.w;
  #pragma unroll
  for (int m = 32; m > 0; m >>= 1) ss += __shfl_xor(ss, m, 64);
  float inv = 1.0f / fmaxf(sqrtf(ss), EPSN);
  ushort8 o;
  o[0]=f2bf(v0.x*inv); o[1]=f2bf(v0.y*inv); o[2]=f2bf(v0.z*inv); o[3]=f2bf(v0.w*inv);
  o[4]=f2bf(v1.x*inv); o[5]=f2bf(v1.y*inv); o[6]=f2bf(v1.z*inv); o[7]=f2bf(v1.w*inv);
  *(ushort8*)(dst + lane * 8) = o;
}

// 128x128-tile GEMM (cos = nx.nw^T) + fused exp-sum.
// R8 skeleton with the LDS diet: A-ONLY through LDS (reg-staged double
// buffer, lgkm-only barrier, no global_load_lds); B fragments go DIRECT
// global->register at prefetch depth 2 — each wave's 64 cols are unique in
// the block, so B never gained from intra-block LDS sharing; cross-block B
// reuse comes from L2 (rtile-fastest grid; FETCH=203 MB proven in R8/R11).
// LDS traffic drops 72 -> 24 KB/block-stage (16 rd + 8 wr b128), and the
// ds_read->MFMA dependency for B disappears (operands already in regs).
// Hazards: ldsA[p^1] writes at stage k safe (all waves' p^1 reads retired at
// their lgkmcnt(0) before barrier k-1); bfr/rA WAR resolved by placing the
// kt+2 prefetch AFTER the MFMAs (arrival slack ~2 stage walls >= HBM lat).
// VGPR ~150 -> __launch_bounds__(256,3) (budget 170; R12 showed tighter
// bounds force catastrophic spills — watch WRITE_SIZE).
// No max-prescan: cos in [-1,1] so exp() is safe; partials are plain sums.
__global__ __launch_bounds__(256, 3) void k_gemm(const unsigned short* __restrict__ nx,
                                                 const unsigned short* __restrict__ nw,
                                                 const int* __restrict__ label,
                                                 float* __restrict__ pl,
                                                 float* __restrict__ tbf) {
  __shared__ bf16x8 ldsA[2][8 * 64];   // 2 x 8 KB

  int rtile = blockIdx.x;              // 0..31 fastest -> B reuse in L2/L3
  int ctile = blockIdx.y;              // 0..392
  int tid = threadIdx.x;
  int wave = tid >> 6;
  int lane = tid & 63;
  int q = lane >> 4;
  int l15 = lane & 15;
  int wr = wave >> 1;
  int wc = wave & 1;
  int rowTile = rtile * 128;
  int colTile = ctile * 128;

  // A staging: wave stages chunks {2w, 2w+1}; chunk c covers rows
  // rowTile + c*16 + l15, elems kt*32 + q*8 .. +7 (16 B/lane).
  const unsigned short* gA[2];
  #pragma unroll
  for (int t = 0; t < 2; t++) {
    int c = wave * 2 + t;
    gA[t] = nx + (size_t)(rowTile + c * 16 + l15) * E_DIM + q * 8;
  }
  // B: this wave's 4 col-subtiles (cols colTile + wc*64 + j*16 + l15).
  const unsigned short* gB[4];
  #pragma unroll
  for (int j = 0; j < 4; j++) {
    int cls = colTile + wc * 64 + j * 16 + l15;
    if (cls >= C_CLS) cls = C_CLS - 1;          // clamp; masked in epilogue
    gB[j] = nw + (size_t)cls * E_DIM + q * 8;
  }

  // Staging registers: parity sets — set s&1 holds stage s data.
  bf16x8 rA[2][2], bfr[2][4];
  #pragma unroll
  for (int t = 0; t < 2; t++) {
    rA[0][t] = *(const bf16x8*)(gA[t]);
    rA[1][t] = *(const bf16x8*)(gA[t] + 32);
  }
  #pragma unroll
  for (int j = 0; j < 4; j++) {
    bfr[0][j] = *(const bf16x8*)(gB[j]);
    bfr[1][j] = *(const bf16x8*)(gB[j] + 32);
  }
  // Write A stage 0 into buf 0 (compiler inserts precise vmcnt waits).
  #pragma unroll
  for (int t = 0; t < 2; t++)
    ldsA[0][(wave * 2 + t) * 64 + lane] = rA[0][t];
  __builtin_amdgcn_s_waitcnt(WAITCNT_LGKM0);
  __builtin_amdgcn_s_barrier();

  f32x4 acc[4][4] = {};

  #pragma unroll
  for (int kt = 0; kt < 16; kt++) {
    int p = kt & 1;
    // A fragments for stage kt (shared tile half wr).
    bf16x8 afr[4];
    #pragma unroll
    for (int i = 0; i < 4; i++)
      afr[i] = ldsA[p][(wr * 4 + i) * 64 + lane];
    // Stage kt+1 A: regs -> buf p^1 (loads issued 1 stage ago).
    if (kt + 1 < 16) {
      #pragma unroll
      for (int t = 0; t < 2; t++)
        ldsA[p ^ 1][(wave * 2 + t) * 64 + lane] = rA[(kt + 1) & 1][t];
    }
    // MFMAs: B operands already in registers (bfr set p), no LDS hop.
    #pragma unroll
    for (int i = 0; i < 4; i++)
      #pragma unroll
      for (int j = 0; j < 4; j++)
        acc[i][j] = __builtin_amdgcn_mfma_f32_16x16x32_bf16(afr[i], bfr[p][j],
                                                            acc[i][j], 0, 0, 0);
    // Stage kt+2 prefetch (after MFMAs: clean WAR on sets rA[p]/bfr[p];
    // arrival slack ~2 stage walls).
    if (kt + 2 < 16) {
      #pragma unroll
      for (int t = 0; t < 2; t++)
        rA[p][t] = *(const bf16x8*)(gA[t] + (kt + 2) * 32);
      #pragma unroll
      for (int j = 0; j < 4; j++)
        bfr[p][j] = *(const bf16x8*)(gB[j] + (kt + 2) * 32);
    }
    __builtin_amdgcn_s_waitcnt(WAITCNT_LGKM0);   // all LDS ops retired (vmcnt free)
    __builtin_amdgcn_s_barrier();
  }

  // Epilogue: C/D layout row = 4*q + reg (within 16), col = l15.
  // Wave covers rows [rowTile + wr*64, +64), cols [colTile + wc*64, +64).
  int colW = colTile + wc * 64;
  #pragma unroll
  for (int msub = 0; msub < 4; msub++) {
    #pragma unroll
    for (int reg = 0; reg < 4; reg++) {
      int grow = rowTile + wr * 64 + msub * 16 + 4 * q + reg;
      int lab = label[grow];
      float e = 0.f;
      #pragma unroll
      for (int ns = 0; ns < 4; ns++) {
        int col = colW + ns * 16 + l15;
        float v = acc[msub][ns][reg];
        if (col < C_CLS) {
          e += __expf(v);
          if (col == lab) tbf[grow] = v;   // bf16-GEMM cos at label position
        }
      }
      #pragma unroll
      for (int m = 1; m < 16; m <<= 1) e += __shfl_xor(e, m, 64);
      if (l15 == 0) pl[(size_t)grow * NCT2 + (size_t)ctile * 2 + wc] = e;
    }
  }
}

// Per row: sum exp-partials, precise fp32 target cosine (fused), swap in
// margin logit, mean-reduce. 1 block/row, 256 thr.
__global__ __launch_bounds__(256) void k_reduce(const float* __restrict__ pl,
                                                const float* __restrict__ x,
                                                const float* __restrict__ w,
                                                const int* __restrict__ label,
                                                const float* __restrict__ tbf,
                                                float* __restrict__ out) {
  int row = blockIdx.x;
  int tid = threadIdx.x;
  int lab = label[row];
  float s = 0.f;
  for (int j = tid; j < NCT2; j += 256) s += pl[(size_t)row * NCT2 + j];
  const float2* px = (const float2*)(x + (size_t)row * E_DIM);
  const float2* pw = (const float2*)(w + (size_t)lab * E_DIM);
  float2 a = px[tid], b = pw[tid];
  float sx = a.x*a.x + a.y*a.y;
  float sw = b.x*b.x + b.y*b.y;
  float sd = a.x*b.x + a.y*b.y;
  #pragma unroll
  for (int off = 32; off > 0; off >>= 1) {
    s  += __shfl_down(s, off, 64);
    sx += __shfl_down(sx, off, 64);
    sw += __shfl_down(sw, off, 64);
    sd += __shfl_down(sd, off, 64);
  }
  __shared__ float sb[4][4];
  if ((tid & 63) == 0) {
    int wv = tid >> 6;
    sb[0][wv] = s; sb[1][wv] = sx; sb[2][wv] = sw; sb[3][wv] = sd;
  }
  __syncthreads();
  if (tid == 0) {
    float S  = sb[0][0] + sb[0][1] + sb[0][2] + sb[0][3];
    float SX = sb[1][0] + sb[1][1] + sb[1][2] + sb[1][3];
    float SW = sb[2][0] + sb[2][1] + sb[2][2] + sb[2][3];
    float SD = sb[3][0] + sb[3][1] + sb[3][2] + sb[3][3];
    float t = SD / (fmaxf(sqrtf(SX), EPSN) * fmaxf(sqrtf(SW), EPSN));
    float tb = tbf[row];
    float sint = sqrtf(fmaxf(0.f, 1.f - t * t));
    float cosm = t * COS_M - sint * SIN_M;
    float Sp = S - __expf(tb) + __expf(cosm);   // replace target logit
    float loss = logf(Sp) - cosm;
    atomicAdd(out, loss * (1.0f / N_ROWS));
  }
}

extern "C" void kernel_launch(void* const* d_in, const int* in_sizes, int n_in,
                              void* d_out, int out_size, void* d_ws, size_t ws_size,
                              hipStream_t stream) {
  const float* x = (const float*)d_in[0];
  const int* label = (const int*)d_in[1];
  const float* w = (const float*)d_in[2];
  float* out = (float*)d_out;
  char* ws = (char*)d_ws;

  size_t off = 0;
  unsigned short* nx = (unsigned short*)(ws + off); off += (size_t)N_ROWS * E_DIM * 2;  // 4 MB
  unsigned short* nw = (unsigned short*)(ws + off); off += (size_t)C_CLS * E_DIM * 2;   // 51.5 MB
  float* tbf = (float*)(ws + off); off += (size_t)N_ROWS * 4;
  float* pl  = (float*)(ws + off); off += (size_t)N_ROWS * NCT2 * 4;                    // 12.9 MB

  hipMemsetAsync(d_out, 0, sizeof(float), stream);
  k_norm<<<(C_CLS + N_ROWS + 3) / 4, 256, 0, stream>>>(w, x, nw, nx);
  dim3 g(N_ROWS / 128, NTILE);
  k_gemm<<<g, 256, 0, stream>>>(nx, nw, label, pl, tbf);
  k_reduce<<<N_ROWS, 256, 0, stream>>>(pl, x, w, label, tbf, out);
}